// Round 2
// baseline (6364.162 us; speedup 1.0000x reference)
//
#include <hip/hip_runtime.h>
#include <hip/hip_bf16.h>

#define T_STEPS 8
#define BATCH 32
#define RR 56
#define MROWS (BATCH*RR)        // 1792
#define H0 2048
#define H1 2048
#define H2 1024
#define D_IN 1024
#define F_OUT (RR*H2)           // 57344
#define MBIG (T_STEPS*MROWS)    // 14336

typedef short short8 __attribute__((ext_vector_type(8)));
typedef float f32x4 __attribute__((ext_vector_type(4)));

__device__ __forceinline__ unsigned short bf16bits(float v) {
    __hip_bfloat16 h = __float2bfloat16(v);
    unsigned short b;
    __builtin_memcpy(&b, &h, 2);
    return b;
}

// ---------- Pool + 3-term bf16 split: x -> featP[3][14336][1024] ----------
__global__ __launch_bounds__(256) void pool_kernel(const float* __restrict__ x,
                                                   __hip_bfloat16* __restrict__ featP) {
    int tid = blockIdx.x * 256 + threadIdx.x;
    const int total = MBIG * 1024;
    if (tid >= total) return;
    int d    = tid & 1023;
    int rest = tid >> 10;
    int r  = rest % RR;
    int tb = rest / RR;
    int b  = tb & 31;
    int t  = tb >> 5;
    int c  = r / 14, tp = r % 14;
    int hp = d >> 5, wp = d & 31;
    int n0 = t * 29 + 2 * tp;
    const float* xp = x + (((size_t)(b * 4 + c) * 232 + n0) * 4096) + (hp * 2) * 64 + (wp * 2);
    float s = 0.f;
    #pragma unroll
    for (int kd = 0; kd < 3; ++kd) {
        const float* xq = xp + (size_t)kd * 4096;
        s += xq[0] + xq[1] + xq[64] + xq[65];
    }
    s *= (1.0f / 12.0f);
    const size_t PS = (size_t)MBIG * 1024;
    __hip_bfloat16 h = __float2bfloat16(s);
    float vh = __bfloat162float(h);
    __hip_bfloat16 m = __float2bfloat16(s - vh);
    float vm = __bfloat162float(m);
    __hip_bfloat16 l = __float2bfloat16(s - vh - vm);
    featP[tid] = h;
    featP[PS + tid] = m;
    featP[2 * PS + tid] = l;
}

// ---------- Weight transpose + split: W[K][N] fp32 -> Wt[3][N][K] bf16 ----------
__global__ __launch_bounds__(256) void wsplit(const float* __restrict__ W,
                                              __hip_bfloat16* __restrict__ Wt,
                                              int K, int N) {
    int idx = blockIdx.x * 256 + threadIdx.x;     // over N * (K/8)
    int kc8 = K >> 3;
    if (idx >= N * kc8) return;
    int n  = idx % N;          // lane-fast -> coalesced reads
    int kc = idx / N;
    short8 h, m, l;
    #pragma unroll
    for (int j = 0; j < 8; ++j) {
        float v = W[(size_t)(kc * 8 + j) * N + n];
        __hip_bfloat16 hb = __float2bfloat16(v);
        float vh = __bfloat162float(hb);
        __hip_bfloat16 mb = __float2bfloat16(v - vh);
        float vm = __bfloat162float(mb);
        __hip_bfloat16 lb = __float2bfloat16(v - vh - vm);
        unsigned short hh, mm2, ll;
        __builtin_memcpy(&hh, &hb, 2); __builtin_memcpy(&mm2, &mb, 2); __builtin_memcpy(&ll, &lb, 2);
        h[j] = (short)hh; m[j] = (short)mm2; l[j] = (short)ll;
    }
    const size_t PS = (size_t)N * K;
    short8* o0 = (short8*)(Wt + (size_t)n * K + kc * 8);
    short8* o1 = (short8*)(Wt + PS + (size_t)n * K + kc * 8);
    short8* o2 = (short8*)(Wt + 2 * PS + (size_t)n * K + kc * 8);
    *o0 = h; *o1 = m; *o2 = l;
}

// ---------- Split-plane bf16 MFMA GEMM, optional fused LIF epilogue ----------
// C[M][N] = sum_q A_plane[qa_q] @ B_plane[qb_q]^T-stored;  A planes [M][K], B planes [N][K]
template<int BM, int BN, int LIF>
__global__ __launch_bounds__(256) void gemm_split(
    const __hip_bfloat16* __restrict__ A, long aPS,
    const __hip_bfloat16* __restrict__ B, long bPS,
    int M, int N, int K, int Q, unsigned qa, unsigned qb,
    float* __restrict__ Cout,
    const float* __restrict__ bias,
    float* __restrict__ mem, __hip_bfloat16* __restrict__ spk,
    const float* __restrict__ betas, int bi,
    const float* __restrict__ thrs, int ti)
{
    constexpr int BK = 32;
    constexpr int SA = 5;                 // float4 slots per LDS row (4 data + 1 pad = 80B)
    constexpr int MT_M = (BM / 2) / 16;
    constexpr int MT_N = (BN / 2) / 16;
    constexpr int A_LD = BM * 4 / 256;
    constexpr int B_LD = BN * 4 / 256;
    __shared__ float4 As4[BM * SA];
    __shared__ float4 Bs4[BN * SA];
    const int tid  = threadIdx.x;
    const int lane = tid & 63, wid = tid >> 6;
    const int wm0 = (wid >> 1) * (BM / 2);
    const int wn0 = (wid & 1) * (BN / 2);
    const int row0 = blockIdx.y * BM, col0 = blockIdx.x * BN;
    const int lr = lane & 15, lg = lane >> 4;

    f32x4 acc[MT_M][MT_N];
    #pragma unroll
    for (int i = 0; i < MT_M; ++i)
        #pragma unroll
        for (int j = 0; j < MT_N; ++j)
            acc[i][j] = (f32x4){0.f, 0.f, 0.f, 0.f};

    for (int q = 0; q < Q; ++q) {
        const __hip_bfloat16* Aq = A + (long)((qa >> (2 * q)) & 3) * aPS;
        const __hip_bfloat16* Bq = B + (long)((qb >> (2 * q)) & 3) * bPS;
        for (int k0 = 0; k0 < K; k0 += BK) {
            float4 ar[A_LD], br[B_LD];
            #pragma unroll
            for (int j = 0; j < A_LD; ++j) {
                int s = tid + 256 * j;
                ar[j] = *(const float4*)(Aq + (long)(row0 + (s >> 2)) * K + k0 + (s & 3) * 8);
            }
            #pragma unroll
            for (int j = 0; j < B_LD; ++j) {
                int s = tid + 256 * j;
                br[j] = *(const float4*)(Bq + (long)(col0 + (s >> 2)) * K + k0 + (s & 3) * 8);
            }
            __syncthreads();
            #pragma unroll
            for (int j = 0; j < A_LD; ++j) { int s = tid + 256 * j; As4[(s >> 2) * SA + (s & 3)] = ar[j]; }
            #pragma unroll
            for (int j = 0; j < B_LD; ++j) { int s = tid + 256 * j; Bs4[(s >> 2) * SA + (s & 3)] = br[j]; }
            __syncthreads();
            short8 af[MT_M], bf[MT_N];
            #pragma unroll
            for (int i = 0; i < MT_M; ++i)
                af[i] = *(const short8*)&As4[(wm0 + i * 16 + lr) * SA + lg];
            #pragma unroll
            for (int i = 0; i < MT_N; ++i)
                bf[i] = *(const short8*)&Bs4[(wn0 + i * 16 + lr) * SA + lg];
            #pragma unroll
            for (int i = 0; i < MT_M; ++i)
                #pragma unroll
                for (int j = 0; j < MT_N; ++j)
                    acc[i][j] = __builtin_amdgcn_mfma_f32_16x16x32_bf16(af[i], bf[j], acc[i][j], 0, 0, 0);
        }
    }

    float beta = 0.f, thr = 0.f;
    if (LIF) {
        beta = fminf(fmaxf(betas[bi], 0.f), 1.f);
        thr = thrs[ti];
    }
    #pragma unroll
    for (int i = 0; i < MT_M; ++i) {
        #pragma unroll
        for (int j = 0; j < MT_N; ++j) {
            #pragma unroll
            for (int r = 0; r < 4; ++r) {
                int m = row0 + wm0 + i * 16 + lg * 4 + r;  // D: row=(lane>>4)*4+reg
                int n = col0 + wn0 + j * 16 + lr;          // D: col=lane&15
                long idx = (long)m * N + n;
                float v = acc[i][j][r];
                if (LIF) {
                    float cur = v + bias[n];
                    float mo = mem[idx];
                    float rs = (mo > thr) ? thr : 0.f;
                    float mn = beta * mo + cur - rs;
                    mem[idx] = mn;
                    spk[idx] = __float2bfloat16((mn - thr > 0.f) ? 1.f : 0.f);
                } else {
                    Cout[idx] = v;
                }
            }
        }
    }
}

// ---------- LIF0 elementwise: cur_in_all[t] + b_in -> mem0, spk_in(bf16) ----------
__global__ __launch_bounds__(256) void lif0_kernel(const float* __restrict__ curAll,
                                                   const float* __restrict__ b_in,
                                                   float* __restrict__ mem,
                                                   __hip_bfloat16* __restrict__ spk,
                                                   const float* __restrict__ betas,
                                                   const float* __restrict__ thrs, int t)
{
    int i = blockIdx.x * 256 + threadIdx.x;
    const int NN = MROWS * H0;
    if (i >= NN) return;
    float cur = curAll[(long)t * NN + i] + b_in[i & (H0 - 1)];
    float beta = fminf(fmaxf(betas[0], 0.f), 1.f);
    float thr = thrs[0];
    float mo = mem[i];
    float rs = (mo > thr) ? thr : 0.f;
    float mn = beta * mo + cur - rs;
    mem[i] = mn;
    spk[i] = __float2bfloat16((mn - thr > 0.f) ? 1.f : 0.f);
}

// ---------- Readout ----------
__global__ __launch_bounds__(256) void out_step(
    const __hip_bfloat16* __restrict__ spk2, const float* __restrict__ W_out,
    const float* __restrict__ b_out, float* __restrict__ m_out,
    float* __restrict__ out, const float* __restrict__ betas, int t)
{
    const int b = blockIdx.x;
    const int tid = threadIdx.x;
    const __hip_bfloat16* s = spk2 + (size_t)b * F_OUT;
    double a0 = 0, a1 = 0, a2 = 0, a3 = 0;
    for (int i = tid; i < F_OUT; i += 256) {
        float sv = __bfloat162float(s[i]);
        const float4 w = *(const float4*)(W_out + (size_t)i * 4);
        a0 += (double)(sv * w.x);
        a1 += (double)(sv * w.y);
        a2 += (double)(sv * w.z);
        a3 += (double)(sv * w.w);
    }
    __shared__ double red[256][4];
    red[tid][0] = a0; red[tid][1] = a1; red[tid][2] = a2; red[tid][3] = a3;
    __syncthreads();
    for (int s2 = 128; s2 > 0; s2 >>= 1) {
        if (tid < s2) {
            red[tid][0] += red[tid + s2][0];
            red[tid][1] += red[tid + s2][1];
            red[tid][2] += red[tid + s2][2];
            red[tid][3] += red[tid + s2][3];
        }
        __syncthreads();
    }
    if (tid < 4) {
        float beta = fminf(fmaxf(betas[3], 0.f), 1.f);
        float cur = (float)red[0][tid] + b_out[tid];
        float mold = m_out[b * 4 + tid];
        float reset = (mold > 1.0f) ? 1.0f : 0.0f;
        float mnew = beta * mold + cur - reset;
        m_out[b * 4 + tid] = mnew;
        out[((size_t)t * BATCH + b) * 4 + tid] = (mnew - 1.0f > 0.0f) ? 1.0f : 0.0f;
    }
}

extern "C" void kernel_launch(void* const* d_in, const int* in_sizes, int n_in,
                              void* d_out, int out_size, void* d_ws, size_t ws_size,
                              hipStream_t stream) {
    const float* x     = (const float*)d_in[0];
    const float* W_in  = (const float*)d_in[1];
    const float* b_in  = (const float*)d_in[2];
    const float* W_h1  = (const float*)d_in[3];
    const float* b_h1  = (const float*)d_in[4];
    const float* W_h2  = (const float*)d_in[5];
    const float* b_h2  = (const float*)d_in[6];
    const float* W_out = (const float*)d_in[7];
    const float* b_out = (const float*)d_in[8];
    const float* betas = (const float*)d_in[9];
    const float* thrs  = (const float*)d_in[10];
    float* out = (float*)d_out;

    char* ws = (char*)d_ws;
    size_t off = 0;
    float* m_in  = (float*)(ws + off); off += (size_t)MROWS * H0 * 4;
    float* m_h1  = (float*)(ws + off); off += (size_t)MROWS * H1 * 4;
    float* m_h2  = (float*)(ws + off); off += (size_t)MROWS * H2 * 4;
    float* m_out = (float*)(ws + off); off += 512;
    size_t zero_bytes = off;                                   // 36,700,672
    __hip_bfloat16* WtIn = (__hip_bfloat16*)(ws + off); off += (size_t)3 * H0 * D_IN * 2;   // 12.6MB
    __hip_bfloat16* WtH1 = (__hip_bfloat16*)(ws + off); off += (size_t)3 * H1 * H0 * 2;     // 25.2MB
    __hip_bfloat16* WtH2 = (__hip_bfloat16*)(ws + off); off += (size_t)3 * H2 * H1 * 2;     // 12.6MB
    __hip_bfloat16* featP = (__hip_bfloat16*)(ws + off); off += (size_t)3 * MBIG * D_IN * 2; // 88MB
    float* curAll = (float*)(ws + off); off += (size_t)MBIG * H0 * 4;                        // 117MB
    __hip_bfloat16* spk_in = (__hip_bfloat16*)(ws + off); off += (size_t)MROWS * H0 * 2;
    __hip_bfloat16* spk1   = (__hip_bfloat16*)(ws + off); off += (size_t)MROWS * H1 * 2;
    __hip_bfloat16* spk2   = (__hip_bfloat16*)(ws + off); off += (size_t)MROWS * H2 * 2;

    hipMemsetAsync(d_ws, 0, zero_bytes, stream);

    // weight transpose+split (once per launch)
    wsplit<<<(H0 * (D_IN / 8) + 255) / 256, 256, 0, stream>>>(W_in, WtIn, D_IN, H0);
    wsplit<<<(H1 * (H0 / 8) + 255) / 256, 256, 0, stream>>>(W_h1, WtH1, H0, H1);
    wsplit<<<(H2 * (H1 / 8) + 255) / 256, 256, 0, stream>>>(W_h2, WtH2, H1, H2);

    // pool -> feat planes
    pool_kernel<<<(MBIG * D_IN + 255) / 256, 256, 0, stream>>>(x, featP);

    // big fc_in GEMM (no recurrence): curAll[14336][2048], 6 split products
    gemm_split<128, 128, 0><<<dim3(H0 / 128, MBIG / 128), 256, 0, stream>>>(
        featP, (long)MBIG * D_IN, WtIn, (long)H0 * D_IN,
        MBIG, H0, D_IN, 6, 0x910u, 0x184u,
        curAll, nullptr, nullptr, nullptr, nullptr, 0, nullptr, 0);

    for (int t = 0; t < T_STEPS; ++t) {
        lif0_kernel<<<(MROWS * H0 + 255) / 256, 256, 0, stream>>>(
            curAll, b_in, m_in, spk_in, betas, thrs, t);
        gemm_split<64, 128, 1><<<dim3(H1 / 128, MROWS / 64), 256, 0, stream>>>(
            spk_in, 0L, WtH1, (long)H1 * H0,
            MROWS, H1, H0, 3, 0u, 0x24u,
            nullptr, b_h1, m_h1, spk1, betas, 1, thrs, 1);
        gemm_split<64, 128, 1><<<dim3(H2 / 128, MROWS / 64), 256, 0, stream>>>(
            spk1, 0L, WtH2, (long)H2 * H1,
            MROWS, H2, H1, 3, 0u, 0x24u,
            nullptr, b_h2, m_h2, spk2, betas, 2, thrs, 2);
        out_step<<<BATCH, 256, 0, stream>>>(spk2, W_out, b_out, m_out, out, betas, t);
    }
    (void)in_sizes; (void)n_in; (void)out_size; (void)ws_size;
}

// Round 3
// 3044.598 us; speedup vs baseline: 2.0903x; 2.0903x over previous
//
#include <hip/hip_runtime.h>
#include <hip/hip_bf16.h>

#define T_STEPS 8
#define BATCH 32
#define RR 56
#define MROWS (BATCH*RR)        // 1792
#define H0 2048
#define H1 2048
#define H2 1024
#define D_IN 1024
#define F_OUT (RR*H2)           // 57344
#define MBIG (T_STEPS*MROWS)    // 14336

typedef short short8 __attribute__((ext_vector_type(8)));
typedef float f32x4 __attribute__((ext_vector_type(4)));

// async global->LDS, 16B per lane; lds base must be wave-uniform (HW scatters lane i at base+16i)
__device__ __forceinline__ void stage16(const __hip_bfloat16* g, __hip_bfloat16* lds) {
    __builtin_amdgcn_global_load_lds(
        (const __attribute__((address_space(1))) unsigned int*)g,
        (__attribute__((address_space(3))) unsigned int*)lds, 16, 0, 0);
}

// ---------- Pool + 3-term bf16 split: x -> featP[3][14336][1024] ----------
__global__ __launch_bounds__(256) void pool_kernel(const float* __restrict__ x,
                                                   __hip_bfloat16* __restrict__ featP) {
    int tid = blockIdx.x * 256 + threadIdx.x;
    const int total = MBIG * 1024;
    if (tid >= total) return;
    int d    = tid & 1023;
    int rest = tid >> 10;
    int r  = rest % RR;
    int tb = rest / RR;
    int b  = tb & 31;
    int t  = tb >> 5;
    int c  = r / 14, tp = r % 14;
    int hp = d >> 5, wp = d & 31;
    int n0 = t * 29 + 2 * tp;
    const float* xp = x + (((size_t)(b * 4 + c) * 232 + n0) * 4096) + (hp * 2) * 64 + (wp * 2);
    float s = 0.f;
    #pragma unroll
    for (int kd = 0; kd < 3; ++kd) {
        const float* xq = xp + (size_t)kd * 4096;
        s += xq[0] + xq[1] + xq[64] + xq[65];
    }
    s *= (1.0f / 12.0f);
    const size_t PS = (size_t)MBIG * 1024;
    __hip_bfloat16 h = __float2bfloat16(s);
    float vh = __bfloat162float(h);
    __hip_bfloat16 m = __float2bfloat16(s - vh);
    float vm = __bfloat162float(m);
    __hip_bfloat16 l = __float2bfloat16(s - vh - vm);
    featP[tid] = h;
    featP[PS + tid] = m;
    featP[2 * PS + tid] = l;
}

// ---------- Weight transpose + split: W[K][N] fp32 -> Wt[3][N][K] bf16 ----------
__global__ __launch_bounds__(256) void wsplit(const float* __restrict__ W,
                                              __hip_bfloat16* __restrict__ Wt,
                                              int K, int N) {
    int idx = blockIdx.x * 256 + threadIdx.x;     // over N * (K/8)
    int kc8 = K >> 3;
    if (idx >= N * kc8) return;
    int n  = idx % N;          // lane-fast -> coalesced reads
    int kc = idx / N;
    short8 h, m, l;
    #pragma unroll
    for (int j = 0; j < 8; ++j) {
        float v = W[(size_t)(kc * 8 + j) * N + n];
        __hip_bfloat16 hb = __float2bfloat16(v);
        float vh = __bfloat162float(hb);
        __hip_bfloat16 mb = __float2bfloat16(v - vh);
        float vm = __bfloat162float(mb);
        __hip_bfloat16 lb = __float2bfloat16(v - vh - vm);
        unsigned short hh, mm2, ll;
        __builtin_memcpy(&hh, &hb, 2); __builtin_memcpy(&mm2, &mb, 2); __builtin_memcpy(&ll, &lb, 2);
        h[j] = (short)hh; m[j] = (short)mm2; l[j] = (short)ll;
    }
    const size_t PS = (size_t)N * K;
    short8* o0 = (short8*)(Wt + (size_t)n * K + kc * 8);
    short8* o1 = (short8*)(Wt + PS + (size_t)n * K + kc * 8);
    short8* o2 = (short8*)(Wt + 2 * PS + (size_t)n * K + kc * 8);
    *o0 = h; *o1 = m; *o2 = l;
}

// ---------- Plane-fused bf16 MFMA GEMM (m97 structure), optional fused LIF ----------
// C[M][N] = sum over masked (pa,pb): A_pa[M][K] @ B_pb[N][K]^T-stored
// PMASK bit (pa*PB+pb) selects a product. All planes staged per k-step.
template<int BM, int BN, int PA, int PB, unsigned PMASK, int LIF>
__global__ __launch_bounds__(256) void gemm_planes(
    const __hip_bfloat16* __restrict__ A, long aPS,
    const __hip_bfloat16* __restrict__ B, long bPS,
    int M, int N, int K,
    float* __restrict__ Cout, const float* __restrict__ bias,
    float* __restrict__ mem, __hip_bfloat16* __restrict__ spk,
    const float* __restrict__ betas, int bi,
    const float* __restrict__ thrs, int ti)
{
    constexpr int BK = 32;
    constexpr int MT_M = BM / 32;     // wave covers BM/2 rows -> MT_M 16-tiles
    constexpr int MT_N = BN / 32;
    __shared__ __align__(16) __hip_bfloat16 As[PA * BM * BK];
    __shared__ __align__(16) __hip_bfloat16 Bs[PB * BN * BK];
    const int tid  = threadIdx.x;
    const int lane = tid & 63, wid = tid >> 6;
    const int lr = lane & 15, lg = lane >> 4;
    const int row0 = blockIdx.y * BM, col0 = blockIdx.x * BN;
    const int wm0 = (wid >> 1) * (BM / 2), wn0 = (wid & 1) * (BN / 2);
    const int grow = lane >> 2;        // row within a 16-row staging chunk
    const int gcol = (lane & 3) * 8;   // bf16 element offset within row

    f32x4 acc[MT_M][MT_N];
    #pragma unroll
    for (int i = 0; i < MT_M; ++i)
        #pragma unroll
        for (int j = 0; j < MT_N; ++j)
            acc[i][j] = (f32x4){0.f, 0.f, 0.f, 0.f};

    constexpr int ACALLS = PA * BM / 16;   // 16 rows (1KB) per wave-call
    constexpr int BCALLS = PB * BN / 16;

    for (int k0 = 0; k0 < K; k0 += BK) {
        for (int j = wid; j < ACALLS; j += 4) {
            int pa = j / (BM / 16), sub = j % (BM / 16);
            const __hip_bfloat16* g = A + (long)pa * aPS
                + (long)(row0 + sub * 16 + grow) * K + k0 + gcol;
            stage16(g, &As[(pa * BM + sub * 16) * BK]);
        }
        for (int j = wid; j < BCALLS; j += 4) {
            int pb = j / (BN / 16), sub = j % (BN / 16);
            const __hip_bfloat16* g = B + (long)pb * bPS
                + (long)(col0 + sub * 16 + grow) * K + k0 + gcol;
            stage16(g, &Bs[(pb * BN + sub * 16) * BK]);
        }
        asm volatile("s_waitcnt vmcnt(0)" ::: "memory");
        __syncthreads();

        short8 af[PA][MT_M], bf[PB][MT_N];
        #pragma unroll
        for (int pa = 0; pa < PA; ++pa)
            #pragma unroll
            for (int i = 0; i < MT_M; ++i)
                af[pa][i] = *(const short8*)&As[(pa * BM + wm0 + i * 16 + lr) * BK + lg * 8];
        #pragma unroll
        for (int pb = 0; pb < PB; ++pb)
            #pragma unroll
            for (int j = 0; j < MT_N; ++j)
                bf[pb][j] = *(const short8*)&Bs[(pb * BN + wn0 + j * 16 + lr) * BK + lg * 8];

        #pragma unroll
        for (int pa = 0; pa < PA; ++pa)
            #pragma unroll
            for (int pb = 0; pb < PB; ++pb)
                if ((PMASK >> (pa * PB + pb)) & 1u) {
                    #pragma unroll
                    for (int i = 0; i < MT_M; ++i)
                        #pragma unroll
                        for (int j = 0; j < MT_N; ++j)
                            acc[i][j] = __builtin_amdgcn_mfma_f32_16x16x32_bf16(
                                af[pa][i], bf[pb][j], acc[i][j], 0, 0, 0);
                }
        __syncthreads();
    }

    float beta = 0.f, thr = 0.f;
    if (LIF) {
        beta = fminf(fmaxf(betas[bi], 0.f), 1.f);
        thr = thrs[ti];
    }
    #pragma unroll
    for (int i = 0; i < MT_M; ++i) {
        #pragma unroll
        for (int j = 0; j < MT_N; ++j) {
            #pragma unroll
            for (int r = 0; r < 4; ++r) {
                int m = row0 + wm0 + i * 16 + lg * 4 + r;  // D: row=(lane>>4)*4+reg
                int n = col0 + wn0 + j * 16 + lr;          // D: col=lane&15
                long idx = (long)m * N + n;
                float v = acc[i][j][r];
                if (LIF) {
                    float cur = v + bias[n];
                    float mo = mem[idx];
                    float rs = (mo > thr) ? thr : 0.f;
                    float mn = beta * mo + cur - rs;
                    mem[idx] = mn;
                    spk[idx] = __float2bfloat16((mn - thr > 0.f) ? 1.f : 0.f);
                } else {
                    Cout[idx] = v;
                }
            }
        }
    }
}

// ---------- LIF0 elementwise ----------
__global__ __launch_bounds__(256) void lif0_kernel(const float* __restrict__ curAll,
                                                   const float* __restrict__ b_in,
                                                   float* __restrict__ mem,
                                                   __hip_bfloat16* __restrict__ spk,
                                                   const float* __restrict__ betas,
                                                   const float* __restrict__ thrs, int t)
{
    int i = blockIdx.x * 256 + threadIdx.x;
    const int NN = MROWS * H0;
    if (i >= NN) return;
    float cur = curAll[(long)t * NN + i] + b_in[i & (H0 - 1)];
    float beta = fminf(fmaxf(betas[0], 0.f), 1.f);
    float thr = thrs[0];
    float mo = mem[i];
    float rs = (mo > thr) ? thr : 0.f;
    float mn = beta * mo + cur - rs;
    mem[i] = mn;
    spk[i] = __float2bfloat16((mn - thr > 0.f) ? 1.f : 0.f);
}

// ---------- Readout ----------
__global__ __launch_bounds__(256) void out_step(
    const __hip_bfloat16* __restrict__ spk2, const float* __restrict__ W_out,
    const float* __restrict__ b_out, float* __restrict__ m_out,
    float* __restrict__ out, const float* __restrict__ betas, int t)
{
    const int b = blockIdx.x;
    const int tid = threadIdx.x;
    const __hip_bfloat16* s = spk2 + (size_t)b * F_OUT;
    double a0 = 0, a1 = 0, a2 = 0, a3 = 0;
    for (int i = tid; i < F_OUT; i += 256) {
        float sv = __bfloat162float(s[i]);
        const float4 w = *(const float4*)(W_out + (size_t)i * 4);
        a0 += (double)(sv * w.x);
        a1 += (double)(sv * w.y);
        a2 += (double)(sv * w.z);
        a3 += (double)(sv * w.w);
    }
    __shared__ double red[256][4];
    red[tid][0] = a0; red[tid][1] = a1; red[tid][2] = a2; red[tid][3] = a3;
    __syncthreads();
    for (int s2 = 128; s2 > 0; s2 >>= 1) {
        if (tid < s2) {
            red[tid][0] += red[tid + s2][0];
            red[tid][1] += red[tid + s2][1];
            red[tid][2] += red[tid + s2][2];
            red[tid][3] += red[tid + s2][3];
        }
        __syncthreads();
    }
    if (tid < 4) {
        float beta = fminf(fmaxf(betas[3], 0.f), 1.f);
        float cur = (float)red[0][tid] + b_out[tid];
        float mold = m_out[b * 4 + tid];
        float reset = (mold > 1.0f) ? 1.0f : 0.0f;
        float mnew = beta * mold + cur - reset;
        m_out[b * 4 + tid] = mnew;
        out[((size_t)t * BATCH + b) * 4 + tid] = (mnew - 1.0f > 0.0f) ? 1.0f : 0.0f;
    }
}

extern "C" void kernel_launch(void* const* d_in, const int* in_sizes, int n_in,
                              void* d_out, int out_size, void* d_ws, size_t ws_size,
                              hipStream_t stream) {
    const float* x     = (const float*)d_in[0];
    const float* W_in  = (const float*)d_in[1];
    const float* b_in  = (const float*)d_in[2];
    const float* W_h1  = (const float*)d_in[3];
    const float* b_h1  = (const float*)d_in[4];
    const float* W_h2  = (const float*)d_in[5];
    const float* b_h2  = (const float*)d_in[6];
    const float* W_out = (const float*)d_in[7];
    const float* b_out = (const float*)d_in[8];
    const float* betas = (const float*)d_in[9];
    const float* thrs  = (const float*)d_in[10];
    float* out = (float*)d_out;

    char* ws = (char*)d_ws;
    size_t off = 0;
    float* m_in  = (float*)(ws + off); off += (size_t)MROWS * H0 * 4;
    float* m_h1  = (float*)(ws + off); off += (size_t)MROWS * H1 * 4;
    float* m_h2  = (float*)(ws + off); off += (size_t)MROWS * H2 * 4;
    float* m_out = (float*)(ws + off); off += 512;
    size_t zero_bytes = off;                                   // 36,700,672
    __hip_bfloat16* WtIn = (__hip_bfloat16*)(ws + off); off += (size_t)3 * H0 * D_IN * 2;
    __hip_bfloat16* WtH1 = (__hip_bfloat16*)(ws + off); off += (size_t)3 * H1 * H0 * 2;
    __hip_bfloat16* WtH2 = (__hip_bfloat16*)(ws + off); off += (size_t)3 * H2 * H1 * 2;
    __hip_bfloat16* featP = (__hip_bfloat16*)(ws + off); off += (size_t)3 * MBIG * D_IN * 2;
    float* curAll = (float*)(ws + off); off += (size_t)MBIG * H0 * 4;
    __hip_bfloat16* spk_in = (__hip_bfloat16*)(ws + off); off += (size_t)MROWS * H0 * 2;
    __hip_bfloat16* spk1   = (__hip_bfloat16*)(ws + off); off += (size_t)MROWS * H1 * 2;
    __hip_bfloat16* spk2   = (__hip_bfloat16*)(ws + off); off += (size_t)MROWS * H2 * 2;

    hipMemsetAsync(d_ws, 0, zero_bytes, stream);

    wsplit<<<(H0 * (D_IN / 8) + 255) / 256, 256, 0, stream>>>(W_in, WtIn, D_IN, H0);
    wsplit<<<(H1 * (H0 / 8) + 255) / 256, 256, 0, stream>>>(W_h1, WtH1, H0, H1);
    wsplit<<<(H2 * (H1 / 8) + 255) / 256, 256, 0, stream>>>(W_h2, WtH2, H1, H2);

    pool_kernel<<<(MBIG * D_IN + 255) / 256, 256, 0, stream>>>(x, featP);

    // fc_in: 6 split products (hh,hm,mh,hl,mm,lh) fused in one K-sweep
    // PMASK bits pa*3+pb for (0,0),(0,1),(0,2),(1,0),(1,1),(2,0) -> 0x5F
    gemm_planes<64, 128, 3, 3, 0x5Fu, 0><<<dim3(H0 / 128, MBIG / 64), 256, 0, stream>>>(
        featP, (long)MBIG * D_IN, WtIn, (long)H0 * D_IN,
        MBIG, H0, D_IN,
        curAll, nullptr, nullptr, nullptr, nullptr, 0, nullptr, 0);

    for (int t = 0; t < T_STEPS; ++t) {
        lif0_kernel<<<(MROWS * H0 + 255) / 256, 256, 0, stream>>>(
            curAll, b_in, m_in, spk_in, betas, thrs, t);
        gemm_planes<64, 128, 1, 3, 0x7u, 1><<<dim3(H1 / 128, MROWS / 64), 256, 0, stream>>>(
            spk_in, 0L, WtH1, (long)H1 * H0,
            MROWS, H1, H0,
            nullptr, b_h1, m_h1, spk1, betas, 1, thrs, 1);
        gemm_planes<64, 128, 1, 3, 0x7u, 1><<<dim3(H2 / 128, MROWS / 64), 256, 0, stream>>>(
            spk1, 0L, WtH2, (long)H2 * H1,
            MROWS, H2, H1,
            nullptr, b_h2, m_h2, spk2, betas, 2, thrs, 2);
        out_step<<<BATCH, 256, 0, stream>>>(spk2, W_out, b_out, m_out, out, betas, t);
    }
    (void)in_sizes; (void)n_in; (void)out_size; (void)ws_size;
}